// Round 7
// baseline (462.604 us; speedup 1.0000x reference)
//
#include <hip/hip_runtime.h>
#include <hip/hip_cooperative_groups.h>
#include <math.h>

namespace cg = cooperative_groups;

// ---------------- problem constants ----------------
constexpr int N_    = 10000;
constexpr int E_    = 320000;
constexpr int IND   = 128;
constexpr int HID   = 32;
constexpr int OUTD  = 128;
constexpr int NIV   = 33;
constexpr float EPS = 1e-5f;

// ---------------- workspace layout (element offsets, 4B each) ----
constexpr size_t OFF_SUMH   = 0;       // 128 f
constexpr size_t OFF_SQH    = 128;     // 128 f
constexpr size_t OFF_SUMP   = 256;     // 32 f
constexpr size_t OFF_SQP    = 288;     // 32 f
constexpr size_t OFF_SUMU   = 320;     // 32 f
constexpr size_t OFF_SQU    = 352;     // 32 f
constexpr size_t OFF_SUMO   = 384;     // 128 f
constexpr size_t OFF_SQO    = 512;     // 128 f
constexpr size_t OFF_OCC    = 640;     // 33 i
constexpr size_t OFF_DEGIN  = 704;     // 10000 i
constexpr size_t OFF_DEGOUT = 10704;   // 10000 i
constexpr size_t ZERO_CNT   = 20704;   // zeroed in phase 0 / memset
constexpr size_t OFF_STARTS = 20740;   // 10001 i
constexpr size_t OFF_CUR    = 30744;   // 10000 i
constexpr size_t OFF_C1     = 40744;   // 33*1056 f
constexpr size_t OFF_C0     = 75592;   // 33*1056 f
constexpr size_t OFF_P      = 110440;  // N*32 f
constexpr size_t OFF_UPD    = 430440;  // N*32 f
constexpr size_t OFF_AEN    = 750440;  // E float2 {a, nin|(iv<<16)} in CSR order

__device__ inline int compute_bps(const float* kw1, const float* kb1, float* bp) {
    int m = 0;
    for (int k = 0; k < 32; ++k) {
        float w = kw1[k];
        if (w != 0.f) bp[m++] = -kb1[k] / w;
    }
    for (int a = 1; a < m; ++a) {
        float v = bp[a]; int b = a - 1;
        while (b >= 0 && bp[b] > v) { bp[b+1] = bp[b]; --b; }
        bp[b+1] = v;
    }
    return m;
}

// =======================================================================
// Mega-kernel: whole pipeline in ONE cooperative dispatch.
// Grid-size-agnostic: every phase loops tasks by gridDim.x.
// =======================================================================
__global__ __launch_bounds__(256)
void k_mega(const float* __restrict__ H, const float* __restrict__ ea,
            const int* __restrict__ edges,
            const float* __restrict__ w1, const float* __restrict__ b1,
            const float* __restrict__ kw1, const float* __restrict__ kb1,
            const float* __restrict__ kw2, const float* __restrict__ kb2,
            const float* __restrict__ w2, const float* __restrict__ b2,
            const float* __restrict__ g_in, const float* __restrict__ beta_in,
            const float* __restrict__ g_msg, const float* __restrict__ beta_msg,
            const float* __restrict__ g_upd, const float* __restrict__ beta_upd,
            const float* __restrict__ g_out, const float* __restrict__ beta_out,
            float* __restrict__ ws, float* __restrict__ out) {
    cg::grid_group grid = cg::this_grid();
    __shared__ float S[6144];          // 24 KiB arena
    __shared__ int s_slots[2];
    int* wsi = (int*)ws;
    const int t = threadIdx.x;
    const int bid = blockIdx.x;
    const int GD  = gridDim.x;

    // ---------------- phase 0: zero accumulators ----------------
    for (size_t i = (size_t)bid*256 + t; i < ZERO_CNT; i += (size_t)GD*256)
        ws[i] = 0.f;
    grid.sync();

    // ---------------- phase A: tables | H stats | edge occ+deg ----------------
    {
        float* sel1 = S;         float* sel0 = S + 32;
        float* shS  = S + 64;    float* shQ  = S + 320;
        int*   locc = (int*)(S + 576);
        float* bps  = S + 640;
        for (int task = bid; task < 474; task += GD) {
            if (task < 33) {
                int i = task;
                if (t == 0) {
                    float bp[32];
                    int m = compute_bps(kw1, kb1, bp);
                    float arep;
                    if (m == 0 || i > m) arep = 0.f;
                    else if (i == 0)     arep = bp[0]   - (1.f + 0.5f*fabsf(bp[0]));
                    else if (i == m)     arep = bp[m-1] + (1.f + 0.5f*fabsf(bp[m-1]));
                    else                 arep = (bp[i-1] < bp[i]) ? 0.5f*(bp[i-1] + bp[i]) : bp[i-1];
                    for (int k = 0; k < 32; ++k) {
                        bool s = (arep * kw1[k] + kb1[k]) > 0.f;
                        sel1[k] = s ? kw1[k] : 0.f;
                        sel0[k] = s ? kb1[k] : 0.f;
                    }
                }
                __syncthreads();
                for (int r = t; r < 1056; r += 256) {
                    float a1 = 0.f, a0 = 0.f;
                    for (int k = 0; k < 32; ++k) {
                        float w = kw2[r*32 + k];
                        a1 += w * sel1[k];
                        a0 += w * sel0[k];
                    }
                    ws[OFF_C1 + (size_t)i*1056 + r] = a1;
                    ws[OFF_C0 + (size_t)i*1056 + r] = a0 + kb2[r];
                }
            } else if (task < 161) {
                int b2 = task - 33;
                int col = t & 127, half = t >> 7;
                float s = 0.f, q = 0.f;
                for (int r = b2*2 + half; r < N_; r += 128*2) {
                    float x = H[(size_t)r*IND + col];
                    s += x; q += x*x;
                }
                shS[t] = s; shQ[t] = q;
                __syncthreads();
                if (t < 128) {
                    atomicAdd(&ws[OFF_SUMH + t], shS[t] + shS[t+128]);
                    atomicAdd(&ws[OFF_SQH  + t], shQ[t] + shQ[t+128]);
                }
            } else {
                int b2 = task - 161;
                if (t < NIV) locc[t] = 0;
                if (t == 0) {
                    float bp[32];
                    int m = compute_bps(kw1, kb1, bp);
                    for (int k = 0; k < 32; ++k) bps[k] = (k < m) ? bp[k] : 3.0e38f;
                }
                __syncthreads();
                for (int e = b2*256 + t; e < E_; e += 313*256) {
                    float a = ea[e];
                    int cnt = 0;
                    #pragma unroll
                    for (int k = 0; k < 32; ++k) cnt += (bps[k] < a) ? 1 : 0;
                    atomicAdd(&locc[cnt], 1);
                    atomicAdd(&wsi[OFF_DEGIN  + edges[E_ + e]], 1);
                    atomicAdd(&wsi[OFF_DEGOUT + edges[e]],      1);
                }
                __syncthreads();
                if (t < NIV && locc[t] > 0) atomicAdd(&wsi[OFF_OCC + t], locc[t]);
            }
            __syncthreads();
        }
    }
    grid.sync();

    // ---------------- phase B: scan (task 0) + nodeP (tasks 1..1250) ----------
    {
        float* w1L  = S;               // 32*129
        float* xl   = S + 4128;        // 8*128
        int*   part = (int*)(S + 5152);
        for (int idx = t; idx < 4096; idx += 256)
            w1L[(idx >> 7)*129 + (idx & 127)] = w1[idx];
        __syncthreads();
        for (int task = bid; task < 1251; task += GD) {
            if (task == 0) {
                // two-pass exclusive scan (no per-thread array -> low VGPR)
                int base = t * 40;
                int s = 0;
                for (int i = 0; i < 40; ++i) {
                    int idx = base + i;
                    s += (idx < N_) ? wsi[OFF_DEGOUT + idx] : 0;
                }
                part[t] = s;
                __syncthreads();
                for (int off = 1; off < 256; off <<= 1) {
                    int add = (t >= off) ? part[t - off] : 0;
                    __syncthreads();
                    part[t] += add;
                    __syncthreads();
                }
                int run = (t > 0) ? part[t-1] : 0;
                for (int i = 0; i < 40; ++i) {
                    int idx = base + i;
                    if (idx <= N_) {
                        wsi[OFF_STARTS + idx] = run;
                        if (idx < N_) {
                            wsi[OFF_CUR + idx] = run;
                            run += wsi[OFF_DEGOUT + idx];
                        }
                    }
                }
            } else {
                int g = t >> 5, j = t & 31;
                int n = (task - 1)*8 + g;
                float* xlg = xl + g*128;
                float4 h4 = ((const float4*)(H + (size_t)n*IND))[j];
                float4 m4 = ((const float4*)(ws + OFF_SUMH))[j];
                float4 q4 = ((const float4*)(ws + OFF_SQH))[j];
                float4 gg = ((const float4*)g_in)[j];
                float4 bb = ((const float4*)beta_in)[j];
                float4 xv;
                {
                    float* hp = (float*)&h4; float* mp = (float*)&m4; float* qp = (float*)&q4;
                    float* gp = (float*)&gg; float* bp = (float*)&bb; float* xp = (float*)&xv;
                    for (int i = 0; i < 4; ++i) {
                        float mean = mp[i] * (1.f/N_);
                        float var  = qp[i] * (1.f/N_) - mean*mean;
                        float istd = 1.f / sqrtf(var + EPS);
                        float gcv = gp[i]*istd, bcv = bp[i] - mean*gcv;
                        xp[i] = fmaxf(fmaf(gcv, hp[i], bcv), 0.f);
                    }
                }
                ((float4*)xlg)[j] = xv;
                __syncthreads();
                float p = b1[j];
                const float* wr = &w1L[j*129];
                #pragma unroll 8
                for (int k = 0; k < 128; ++k) p = fmaf(wr[k], xlg[k], p);
                ws[OFF_P + (size_t)n*HID + j] = p;
            }
            __syncthreads();
        }
    }
    grid.sync();

    // ---------------- phase C: AEN scatter | msg stats ----------------
    {
        float* bps = S;
        float* shS = S + 64;  float* shQ = S + 320;
        for (int task = bid; task < 377; task += GD) {
            if (task < 313) {
                if (t == 0) {
                    float bp[32];
                    int m = compute_bps(kw1, kb1, bp);
                    for (int k = 0; k < 32; ++k) bps[k] = (k < m) ? bp[k] : 3.0e38f;
                }
                __syncthreads();
                float2* aen = (float2*)(ws + OFF_AEN);
                for (int e = task*256 + t; e < E_; e += 313*256) {
                    int   nout = edges[e];
                    int   nin  = edges[E_ + e];
                    float a    = ea[e];
                    int iv = 0;
                    #pragma unroll
                    for (int k = 0; k < 32; ++k) iv += (bps[k] < a) ? 1 : 0;
                    int pos = atomicAdd(&wsi[OFF_CUR + nout], 1);
                    float2 rec; rec.x = a; rec.y = __int_as_float(nin | (iv << 16));
                    aen[pos] = rec;
                }
            } else {
                int b2 = task - 313;
                int j = t & 31, cp = t >> 5;
                float s = 0.f, q = 0.f;
                for (int n = b2*8 + cp; n < N_; n += 64*8) {
                    float w = (float)wsi[OFF_DEGIN + n];
                    float p = ws[OFF_P + (size_t)n*HID + j];
                    s += w*p; q += w*p*p;
                }
                shS[t] = s; shQ[t] = q;
                __syncthreads();
                if (t < 32) {
                    float Sm = 0.f, Qq = 0.f;
                    for (int c = 0; c < 8; ++c) { Sm += shS[t + 32*c]; Qq += shQ[t + 32*c]; }
                    atomicAdd(&ws[OFF_SUMP + t], Sm);
                    atomicAdd(&ws[OFF_SQP  + t], Qq);
                }
            }
            __syncthreads();
        }
    }
    grid.sync();

    // ---------------- phase D: segment reduce (R4 structure, 8-deep MLP) ------
    {
        float* A   = S;          // 4 x (32*33)
        float* Bv  = S + 4224;   // 4 x 32
        float* zl  = S + 4352;   // 8 x 4 x 32
        float* shS = S + 5376;   float* shQ = S + 5632;
        int g = t >> 5, j = t & 31;
        if (t == 0) {
            int a0 = -1, a1 = -1;
            for (int i = 0; i < NIV; ++i)
                if (wsi[OFF_OCC + i] > 0) { if (a0 < 0) a0 = i; else if (a1 < 0) a1 = i; }
            s_slots[0] = a0; s_slots[1] = a1;
        }
        __syncthreads();
        int s0 = s_slots[0], s1 = s_slots[1];
        for (int idx = t; idx < 1024; idx += 256) {
            int jj = idx >> 5, kk = idx & 31;
            A[0*1056 + jj*33+kk] = (s0 >= 0) ? ws[OFF_C1 + (size_t)s0*1056 + 32 + idx] : 0.f;
            A[1*1056 + jj*33+kk] = (s0 >= 0) ? ws[OFF_C0 + (size_t)s0*1056 + 32 + idx] : 0.f;
            A[2*1056 + jj*33+kk] = (s1 >= 0) ? ws[OFF_C1 + (size_t)s1*1056 + 32 + idx] : 0.f;
            A[3*1056 + jj*33+kk] = (s1 >= 0) ? ws[OFF_C0 + (size_t)s1*1056 + 32 + idx] : 0.f;
        }
        if (t < 32) {
            Bv[0*32+t] = (s0 >= 0) ? ws[OFF_C1 + (size_t)s0*1056 + t] : 0.f;
            Bv[1*32+t] = (s0 >= 0) ? ws[OFF_C0 + (size_t)s0*1056 + t] : 0.f;
            Bv[2*32+t] = (s1 >= 0) ? ws[OFF_C1 + (size_t)s1*1056 + t] : 0.f;
            Bv[3*32+t] = (s1 >= 0) ? ws[OFF_C0 + (size_t)s1*1056 + t] : 0.f;
        }
        float mP = ws[OFF_SUMP + j] * (1.f/E_);
        float vP = ws[OFF_SQP  + j] * (1.f/E_) - mP*mP;
        float istd = 1.f / sqrtf(vP + EPS);
        float gc = g_msg[j]*istd, bc = beta_msg[j] - mP*gc;
        __syncthreads();

        float sumS = 0.f, sumQ = 0.f;
        const float2* aen = (const float2*)(ws + OFF_AEN);
        for (int task = bid; task < 1250; task += GD) {
            int n = task*8 + g;
            int st = wsi[OFF_STARTS + n], en = wsi[OFF_STARTS + n + 1];
            float za0 = 0.f, zb0 = 0.f, za1 = 0.f, zb1 = 0.f;
            float suma0 = 0.f, suma1 = 0.f, c0f = 0.f, c1f = 0.f, rfall = 0.f;
            for (int base = st; base < en; base += 32) {
                int cnt = en - base; if (cnt > 32) cnt = 32;
                float a_j = 0.f; int meta_j = 0;
                if (j < cnt) {
                    float2 r = aen[base + j];
                    a_j = r.x; meta_j = __float_as_int(r.y);
                }
                for (int k = 0; k < cnt; k += 8) {
                    float pv[8], aa[8]; int ivv[8]; bool val[8];
                    #pragma unroll
                    for (int u = 0; u < 8; ++u) {
                        int kk = (k + u) & 31;
                        aa[u]  = __shfl(a_j, kk, 32);
                        int mt = __shfl(meta_j, kk, 32);
                        val[u] = (k + u) < cnt;
                        int nin = mt & 0xFFFF; ivv[u] = mt >> 16;
                        pv[u] = ws[OFF_P + (size_t)nin*HID + j];
                    }
                    #pragma unroll
                    for (int u = 0; u < 8; ++u) {
                        float qv = fmaxf(fmaf(gc, pv[u], bc), 0.f);
                        float a = aa[u]; int iv = ivv[u];
                        if (__builtin_expect(val[u] && iv != s0 && iv != s1, 0)) {
                            // general fallback (not taken with given inputs)
                            const float* C1r = ws + OFF_C1 + (size_t)iv*1056;
                            const float* C0r = ws + OFF_C0 + (size_t)iv*1056;
                            float d1 = 0.f, d0 = 0.f;
                            for (int k2 = 0; k2 < 32; ++k2) {
                                float qk = __shfl(qv, k2, 32);
                                d1 += C1r[32 + j*32 + k2] * qk;
                                d0 += C0r[32 + j*32 + k2] * qk;
                            }
                            rfall += a*(d1 + C1r[j]) + (d0 + C0r[j]);
                        } else {
                            float w0 = (val[u] && iv == s0) ? 1.f : 0.f;
                            float w1v = (val[u] && iv == s1) ? 1.f : 0.f;
                            float w0a = w0 * a, w1a = w1v * a;
                            za0 = fmaf(w0a, qv, za0); zb0 = fmaf(w0, qv, zb0);
                            za1 = fmaf(w1a, qv, za1); zb1 = fmaf(w1v, qv, zb1);
                            suma0 += w0a; c0f += w0;
                            suma1 += w1a; c1f += w1v;
                        }
                    }
                }
            }
            zl[(g*4+0)*32+j] = za0; zl[(g*4+1)*32+j] = zb0;
            zl[(g*4+2)*32+j] = za1; zl[(g*4+3)*32+j] = zb1;
            __syncthreads();
            float acc = rfall;
            if (s0 >= 0) acc += suma0*Bv[0*32+j] + c0f*Bv[1*32+j];
            if (s1 >= 0) acc += suma1*Bv[2*32+j] + c1f*Bv[3*32+j];
            const float* z0 = zl + (g*4+0)*32; const float* z1 = zl + (g*4+1)*32;
            const float* z2 = zl + (g*4+2)*32; const float* z3 = zl + (g*4+3)*32;
            #pragma unroll 4
            for (int k = 0; k < 32; ++k) {
                acc += A[0*1056 + j*33+k]*z0[k] + A[1*1056 + j*33+k]*z1[k]
                     + A[2*1056 + j*33+k]*z2[k] + A[3*1056 + j*33+k]*z3[k];
            }
            ws[OFF_UPD + (size_t)n*HID + j] = acc;
            sumS += acc; sumQ += acc*acc;
            __syncthreads();
        }
        shS[t] = sumS; shQ[t] = sumQ;
        __syncthreads();
        if (t < 32) {
            float Sm = 0.f, Qq = 0.f;
            for (int c = 0; c < 8; ++c) { Sm += shS[t + 32*c]; Qq += shQ[t + 32*c]; }
            atomicAdd(&ws[OFF_SUMU + t], Sm);
            atomicAdd(&ws[OFF_SQU  + t], Qq);
        }
    }
    grid.sync();

    // ---------------- phase F: out = relu(bn(upd)) @ w2.T + b2 ; out stats ----
    {
        float* U   = S;        // 2 x 32
        float* shS = S + 64;   float* shQ = S + 320;
        int nh = t >> 7, o = t & 127;
        float gc = 0.f, bc = 0.f;
        if (o < 32) {
            float m = ws[OFF_SUMU + o]*(1.f/N_);
            float v = ws[OFF_SQU  + o]*(1.f/N_) - m*m;
            float istd = 1.f/sqrtf(v + EPS);
            gc = g_upd[o]*istd; bc = beta_upd[o] - m*gc;
        }
        float w2r[32];
        for (int k = 0; k < 32; ++k) w2r[k] = w2[o*32 + k];
        float bo = b2[o];
        float sO = 0.f, qO = 0.f;
        for (int task = bid; task < 5000; task += GD) {
            int n = task*2 + nh;
            if (o < 32) {
                float u = ws[OFF_UPD + (size_t)n*HID + o];
                U[nh*32 + o] = fmaxf(fmaf(gc, u, bc), 0.f);
            }
            __syncthreads();
            float v = bo;
            for (int k = 0; k < 32; ++k) v = fmaf(w2r[k], U[nh*32 + k], v);
            out[(size_t)n*OUTD + o] = v;
            sO += v; qO += v*v;
            __syncthreads();
        }
        shS[t] = sO; shQ[t] = qO;
        __syncthreads();
        if (t < 128) {
            atomicAdd(&ws[OFF_SUMO + t], shS[t] + shS[t+128]);
            atomicAdd(&ws[OFF_SQO  + t], shQ[t] + shQ[t+128]);
        }
    }
    grid.sync();

    // ---------------- phase G: final output BN (in-place) ----------------
    for (size_t i = (size_t)bid*256 + t; i < (size_t)N_*OUTD; i += (size_t)GD*256) {
        int o = (int)(i & 127);
        float m = ws[OFF_SUMO + o]*(1.f/N_);
        float v = ws[OFF_SQO  + o]*(1.f/N_) - m*m;
        float istd = 1.f/sqrtf(v + EPS);
        out[i] = g_out[o]*istd*(out[i] - m) + beta_out[o];
    }
}

// =======================================================================
// Fallback pipeline (R4 six-kernel version) — used only if the
// cooperative launch is rejected.
// =======================================================================
__global__ __launch_bounds__(256)
void k_A(const float* __restrict__ H,
         const float* __restrict__ ea, const int* __restrict__ edges,
         const float* __restrict__ kw1, const float* __restrict__ kb1,
         const float* __restrict__ kw2, const float* __restrict__ kb2,
         float* __restrict__ ws) {
    __shared__ float sel1[32], sel0[32];
    __shared__ float shS[256], shQ[256];
    __shared__ int locc[NIV];
    __shared__ float bps[32];
    int* wsi = (int*)ws;
    int t = threadIdx.x;
    int bid = blockIdx.x;
    if (bid < 33) {
        int i = bid;
        if (t == 0) {
            float bp[32];
            int m = compute_bps(kw1, kb1, bp);
            float arep;
            if (m == 0 || i > m) arep = 0.f;
            else if (i == 0)     arep = bp[0]   - (1.f + 0.5f*fabsf(bp[0]));
            else if (i == m)     arep = bp[m-1] + (1.f + 0.5f*fabsf(bp[m-1]));
            else                 arep = (bp[i-1] < bp[i]) ? 0.5f*(bp[i-1] + bp[i]) : bp[i-1];
            for (int k = 0; k < 32; ++k) {
                bool s = (arep * kw1[k] + kb1[k]) > 0.f;
                sel1[k] = s ? kw1[k] : 0.f;
                sel0[k] = s ? kb1[k] : 0.f;
            }
        }
        __syncthreads();
        for (int r = t; r < 1056; r += 256) {
            float a1 = 0.f, a0 = 0.f;
            for (int k = 0; k < 32; ++k) {
                float w = kw2[r*32 + k];
                a1 += w * sel1[k];
                a0 += w * sel0[k];
            }
            ws[OFF_C1 + (size_t)i*1056 + r] = a1;
            ws[OFF_C0 + (size_t)i*1056 + r] = a0 + kb2[r];
        }
    } else if (bid < 161) {
        int b2 = bid - 33;
        int col = t & 127, half = t >> 7;
        float s = 0.f, q = 0.f;
        for (int r = b2*2 + half; r < N_; r += 128*2) {
            float x = H[(size_t)r*IND + col];
            s += x; q += x*x;
        }
        shS[t] = s; shQ[t] = q;
        __syncthreads();
        if (t < 128) {
            atomicAdd(&ws[OFF_SUMH + t], shS[t] + shS[t+128]);
            atomicAdd(&ws[OFF_SQH  + t], shQ[t] + shQ[t+128]);
        }
    } else {
        int b2 = bid - 161;
        if (t < NIV) locc[t] = 0;
        if (t == 0) {
            float bp[32];
            int m = compute_bps(kw1, kb1, bp);
            for (int k = 0; k < 32; ++k) bps[k] = (k < m) ? bp[k] : 3.0e38f;
        }
        __syncthreads();
        for (int e = b2*256 + t; e < E_; e += 313*256) {
            float a = ea[e];
            int cnt = 0;
            #pragma unroll
            for (int k = 0; k < 32; ++k) cnt += (bps[k] < a) ? 1 : 0;
            atomicAdd(&locc[cnt], 1);
            atomicAdd(&wsi[OFF_DEGIN  + edges[E_ + e]], 1);
            atomicAdd(&wsi[OFF_DEGOUT + edges[e]],      1);
        }
        __syncthreads();
        if (t < NIV && locc[t] > 0) atomicAdd(&wsi[OFF_OCC + t], locc[t]);
    }
}

__global__ __launch_bounds__(256)
void k_B(const float* __restrict__ H, const float* __restrict__ w1,
         const float* __restrict__ b1, const float* __restrict__ g_in,
         const float* __restrict__ beta_in, float* __restrict__ ws) {
    __shared__ float w1L[32*129];
    __shared__ float xl[8][128];
    __shared__ int part[256];
    int* wsi = (int*)ws;
    int t = threadIdx.x;
    if (blockIdx.x == 0) {
        int base = t * 40;
        int s = 0;
        for (int i = 0; i < 40; ++i) {
            int idx = base + i;
            s += (idx < N_) ? wsi[OFF_DEGOUT + idx] : 0;
        }
        part[t] = s;
        __syncthreads();
        for (int off = 1; off < 256; off <<= 1) {
            int add = (t >= off) ? part[t - off] : 0;
            __syncthreads();
            part[t] += add;
            __syncthreads();
        }
        int run = (t > 0) ? part[t-1] : 0;
        for (int i = 0; i < 40; ++i) {
            int idx = base + i;
            if (idx <= N_) {
                wsi[OFF_STARTS + idx] = run;
                if (idx < N_) { wsi[OFF_CUR + idx] = run; run += wsi[OFF_DEGOUT + idx]; }
            }
        }
        return;
    }
    int g = t >> 5, j = t & 31;
    for (int idx = t; idx < 4096; idx += 256)
        w1L[(idx >> 7)*129 + (idx & 127)] = w1[idx];
    int n = (blockIdx.x - 1)*8 + g;
    float4 h4 = ((const float4*)(H + (size_t)n*IND))[j];
    float4 m4 = ((const float4*)(ws + OFF_SUMH))[j];
    float4 q4 = ((const float4*)(ws + OFF_SQH))[j];
    float4 gg = ((const float4*)g_in)[j];
    float4 bb = ((const float4*)beta_in)[j];
    float4 xv;
    {
        float* hp = (float*)&h4; float* mp = (float*)&m4; float* qp = (float*)&q4;
        float* gp = (float*)&gg; float* bp = (float*)&bb; float* xp = (float*)&xv;
        for (int i = 0; i < 4; ++i) {
            float mean = mp[i] * (1.f/N_);
            float var  = qp[i] * (1.f/N_) - mean*mean;
            float istd = 1.f / sqrtf(var + EPS);
            float gc = gp[i]*istd, bc = bp[i] - mean*gc;
            xp[i] = fmaxf(fmaf(gc, hp[i], bc), 0.f);
        }
    }
    ((float4*)&xl[g][0])[j] = xv;
    __syncthreads();
    float p = b1[j];
    const float* wr = &w1L[j*129];
    const float* xr = &xl[g][0];
    #pragma unroll 8
    for (int k = 0; k < 128; ++k) p = fmaf(wr[k], xr[k], p);
    ws[OFF_P + (size_t)n*HID + j] = p;
}

__global__ __launch_bounds__(256)
void k_C(const float* __restrict__ ea, const int* __restrict__ edges,
         const float* __restrict__ kw1, const float* __restrict__ kb1,
         float* __restrict__ ws) {
    __shared__ float shS[256], shQ[256];
    __shared__ float bps[32];
    int* wsi = (int*)ws;
    int t = threadIdx.x;
    if (blockIdx.x < 313) {
        if (t == 0) {
            float bp[32];
            int m = compute_bps(kw1, kb1, bp);
            for (int k = 0; k < 32; ++k) bps[k] = (k < m) ? bp[k] : 3.0e38f;
        }
        __syncthreads();
        float2* aen = (float2*)(ws + OFF_AEN);
        int b2 = blockIdx.x;
        for (int e = b2*256 + t; e < E_; e += 313*256) {
            int   nout = edges[e];
            int   nin  = edges[E_ + e];
            float a    = ea[e];
            int iv = 0;
            #pragma unroll
            for (int k = 0; k < 32; ++k) iv += (bps[k] < a) ? 1 : 0;
            int pos = atomicAdd(&wsi[OFF_CUR + nout], 1);
            float2 rec; rec.x = a; rec.y = __int_as_float(nin | (iv << 16));
            aen[pos] = rec;
        }
    } else {
        int b2 = blockIdx.x - 313;
        int j = t & 31, cp = t >> 5;
        float s = 0.f, q = 0.f;
        for (int n = b2*8 + cp; n < N_; n += 64*8) {
            float w = (float)wsi[OFF_DEGIN + n];
            float p = ws[OFF_P + (size_t)n*HID + j];
            s += w*p; q += w*p*p;
        }
        shS[t] = s; shQ[t] = q;
        __syncthreads();
        if (t < 32) {
            float S = 0.f, Qq = 0.f;
            for (int c = 0; c < 8; ++c) { S += shS[t + 32*c]; Qq += shQ[t + 32*c]; }
            atomicAdd(&ws[OFF_SUMP + t], S);
            atomicAdd(&ws[OFF_SQP  + t], Qq);
        }
    }
}

__global__ __launch_bounds__(256)
void k_D(const float* __restrict__ g_msg, const float* __restrict__ beta_msg,
         float* __restrict__ ws) {
    __shared__ float A[4][32*33];
    __shared__ float Bv[4][32];
    __shared__ float zl[8][4][32];
    __shared__ float shS[256], shQ[256];
    __shared__ int s_slot0, s_slot1;
    int* wsi = (int*)ws;
    int t = threadIdx.x, g = t >> 5, j = t & 31;
    if (t == 0) {
        int a0 = -1, a1 = -1;
        for (int i = 0; i < NIV; ++i)
            if (wsi[OFF_OCC + i] > 0) { if (a0 < 0) a0 = i; else if (a1 < 0) a1 = i; }
        s_slot0 = a0; s_slot1 = a1;
    }
    __syncthreads();
    int s0 = s_slot0, s1 = s_slot1;
    for (int idx = t; idx < 1024; idx += 256) {
        int jj = idx >> 5, kk = idx & 31;
        A[0][jj*33+kk] = (s0 >= 0) ? ws[OFF_C1 + (size_t)s0*1056 + 32 + idx] : 0.f;
        A[1][jj*33+kk] = (s0 >= 0) ? ws[OFF_C0 + (size_t)s0*1056 + 32 + idx] : 0.f;
        A[2][jj*33+kk] = (s1 >= 0) ? ws[OFF_C1 + (size_t)s1*1056 + 32 + idx] : 0.f;
        A[3][jj*33+kk] = (s1 >= 0) ? ws[OFF_C0 + (size_t)s1*1056 + 32 + idx] : 0.f;
    }
    if (t < 32) {
        Bv[0][t] = (s0 >= 0) ? ws[OFF_C1 + (size_t)s0*1056 + t] : 0.f;
        Bv[1][t] = (s0 >= 0) ? ws[OFF_C0 + (size_t)s0*1056 + t] : 0.f;
        Bv[2][t] = (s1 >= 0) ? ws[OFF_C1 + (size_t)s1*1056 + t] : 0.f;
        Bv[3][t] = (s1 >= 0) ? ws[OFF_C0 + (size_t)s1*1056 + t] : 0.f;
    }
    float mP = ws[OFF_SUMP + j] * (1.f/E_);
    float vP = ws[OFF_SQP  + j] * (1.f/E_) - mP*mP;
    float istd = 1.f / sqrtf(vP + EPS);
    float gc = g_msg[j]*istd, bc = beta_msg[j] - mP*gc;
    __syncthreads();
    int n = blockIdx.x*8 + g;
    int st = wsi[OFF_STARTS + n], en = wsi[OFF_STARTS + n + 1];
    float za0 = 0.f, zb0 = 0.f, za1 = 0.f, zb1 = 0.f;
    float suma0 = 0.f, suma1 = 0.f, c0f = 0.f, c1f = 0.f, rfall = 0.f;
    const float2* aen = (const float2*)(ws + OFF_AEN);
    for (int base = st; base < en; base += 32) {
        int cnt = en - base; if (cnt > 32) cnt = 32;
        float a_j = 0.f; int meta_j = 0;
        if (j < cnt) {
            float2 r = aen[base + j];
            a_j = r.x; meta_j = __float_as_int(r.y);
        }
        for (int k = 0; k < cnt; k += 8) {
            float pv[8], aa[8]; int ivv[8]; bool val[8];
            #pragma unroll
            for (int u = 0; u < 8; ++u) {
                int kk = (k + u) & 31;
                aa[u]  = __shfl(a_j, kk, 32);
                int mt = __shfl(meta_j, kk, 32);
                val[u] = (k + u) < cnt;
                int nin = mt & 0xFFFF; ivv[u] = mt >> 16;
                pv[u] = ws[OFF_P + (size_t)nin*HID + j];
            }
            #pragma unroll
            for (int u = 0; u < 8; ++u) {
                float qv = fmaxf(fmaf(gc, pv[u], bc), 0.f);
                float a = aa[u]; int iv = ivv[u];
                if (__builtin_expect(val[u] && iv != s0 && iv != s1, 0)) {
                    const float* C1r = ws + OFF_C1 + (size_t)iv*1056;
                    const float* C0r = ws + OFF_C0 + (size_t)iv*1056;
                    float d1 = 0.f, d0 = 0.f;
                    for (int k2 = 0; k2 < 32; ++k2) {
                        float qk = __shfl(qv, k2, 32);
                        d1 += C1r[32 + j*32 + k2] * qk;
                        d0 += C0r[32 + j*32 + k2] * qk;
                    }
                    rfall += a*(d1 + C1r[j]) + (d0 + C0r[j]);
                } else {
                    float w0 = (val[u] && iv == s0) ? 1.f : 0.f;
                    float w1v = (val[u] && iv == s1) ? 1.f : 0.f;
                    float w0a = w0 * a, w1a = w1v * a;
                    za0 = fmaf(w0a, qv, za0); zb0 = fmaf(w0, qv, zb0);
                    za1 = fmaf(w1a, qv, za1); zb1 = fmaf(w1v, qv, zb1);
                    suma0 += w0a; c0f += w0;
                    suma1 += w1a; c1f += w1v;
                }
            }
        }
    }
    zl[g][0][j] = za0; zl[g][1][j] = zb0; zl[g][2][j] = za1; zl[g][3][j] = zb1;
    __syncthreads();
    float acc = rfall;
    if (s0 >= 0) acc += suma0*Bv[0][j] + c0f*Bv[1][j];
    if (s1 >= 0) acc += suma1*Bv[2][j] + c1f*Bv[3][j];
    const float* z0 = zl[g][0]; const float* z1 = zl[g][1];
    const float* z2 = zl[g][2]; const float* z3 = zl[g][3];
    #pragma unroll 4
    for (int k = 0; k < 32; ++k) {
        acc += A[0][j*33+k]*z0[k] + A[1][j*33+k]*z1[k]
             + A[2][j*33+k]*z2[k] + A[3][j*33+k]*z3[k];
    }
    ws[OFF_UPD + (size_t)n*HID + j] = acc;
    shS[t] = acc; shQ[t] = acc*acc;
    __syncthreads();
    if (t < 32) {
        float S = 0.f, Qq = 0.f;
        for (int c = 0; c < 8; ++c) { S += shS[t + 32*c]; Qq += shQ[t + 32*c]; }
        atomicAdd(&ws[OFF_SUMU + t], S);
        atomicAdd(&ws[OFF_SQU  + t], Qq);
    }
}

__global__ __launch_bounds__(256)
void k_F(const float* __restrict__ w2, const float* __restrict__ b2,
         const float* __restrict__ g_upd, const float* __restrict__ beta_upd,
         float* __restrict__ ws, float* __restrict__ out) {
    __shared__ float U[2][HID];
    __shared__ float shS[256], shQ[256];
    int t = threadIdx.x, nh = t >> 7, o = t & 127;
    float gc = 0.f, bc = 0.f;
    if (o < 32) {
        float m = ws[OFF_SUMU + o]*(1.f/N_);
        float v = ws[OFF_SQU  + o]*(1.f/N_) - m*m;
        float istd = 1.f/sqrtf(v + EPS);
        gc = g_upd[o]*istd; bc = beta_upd[o] - m*gc;
    }
    float w2r[32];
    for (int k = 0; k < 32; ++k) w2r[k] = w2[o*32 + k];
    float bo = b2[o];
    float sO = 0.f, qO = 0.f;
    for (int base = blockIdx.x*2; base < N_; base += gridDim.x*2) {
        int n = base + nh;
        if (o < 32) {
            float u = ws[OFF_UPD + (size_t)n*HID + o];
            U[nh][o] = fmaxf(fmaf(gc, u, bc), 0.f);
        }
        __syncthreads();
        float v = bo;
        for (int k = 0; k < 32; ++k) v = fmaf(w2r[k], U[nh][k], v);
        out[(size_t)n*OUTD + o] = v;
        sO += v; qO += v*v;
        __syncthreads();
    }
    shS[t] = sO; shQ[t] = qO;
    __syncthreads();
    if (t < 128) {
        atomicAdd(&ws[OFF_SUMO + t], shS[t] + shS[t+128]);
        atomicAdd(&ws[OFF_SQO  + t], shQ[t] + shQ[t+128]);
    }
}

__global__ __launch_bounds__(256)
void k_G(const float* __restrict__ g_out, const float* __restrict__ beta_out,
         const float* __restrict__ ws, float* __restrict__ out) {
    int g = blockIdx.x*blockDim.x + threadIdx.x;
    if (g >= N_*OUTD) return;
    int o = g & 127;
    float m = ws[OFF_SUMO + o]*(1.f/N_);
    float v = ws[OFF_SQO  + o]*(1.f/N_) - m*m;
    float istd = 1.f/sqrtf(v + EPS);
    out[g] = g_out[o]*istd*(out[g] - m) + beta_out[o];
}

// ---------------- launch -----------------------------------------------------
extern "C" void kernel_launch(void* const* d_in, const int* in_sizes, int n_in,
                              void* d_out, int out_size, void* d_ws, size_t ws_size,
                              hipStream_t stream) {
    const float* H        = (const float*)d_in[0];
    const float* ea       = (const float*)d_in[1];
    const int*   edges    = (const int*)  d_in[2];
    const float* w1       = (const float*)d_in[3];
    const float* b1       = (const float*)d_in[4];
    const float* kw1      = (const float*)d_in[5];
    const float* kb1      = (const float*)d_in[6];
    const float* kw2      = (const float*)d_in[7];
    const float* kb2      = (const float*)d_in[8];
    const float* w2       = (const float*)d_in[9];
    const float* b2       = (const float*)d_in[10];
    const float* g_in     = (const float*)d_in[11];
    const float* beta_in  = (const float*)d_in[12];
    const float* g_msg    = (const float*)d_in[13];
    const float* beta_msg = (const float*)d_in[14];
    const float* g_upd    = (const float*)d_in[15];
    const float* beta_upd = (const float*)d_in[16];
    const float* g_out    = (const float*)d_in[17];
    const float* beta_out = (const float*)d_in[18];
    float* ws  = (float*)d_ws;
    float* out = (float*)d_out;

    // co-residency-safe grid size from the occupancy API (deterministic)
    int perCU = 0;
    hipError_t oerr = hipOccupancyMaxActiveBlocksPerMultiprocessor(&perCU, k_mega, 256, 0);
    int blocks = (oerr == hipSuccess && perCU > 0) ? perCU * 256 : 0;
    if (blocks > 512) blocks = 512;

    hipError_t lerr = hipErrorUnknown;
    if (blocks > 0) {
        void* args[] = {
            (void*)&H, (void*)&ea, (void*)&edges, (void*)&w1, (void*)&b1,
            (void*)&kw1, (void*)&kb1, (void*)&kw2, (void*)&kb2,
            (void*)&w2, (void*)&b2, (void*)&g_in, (void*)&beta_in,
            (void*)&g_msg, (void*)&beta_msg, (void*)&g_upd, (void*)&beta_upd,
            (void*)&g_out, (void*)&beta_out, (void*)&ws, (void*)&out
        };
        lerr = hipLaunchCooperativeKernel((void*)k_mega, dim3(blocks), dim3(256),
                                          args, 0, stream);
    }
    if (lerr != hipSuccess) {
        // fallback: proven six-kernel pipeline
        hipMemsetAsync(d_ws, 0, ZERO_CNT*sizeof(float), stream);
        hipLaunchKernelGGL(k_A, dim3(474),  dim3(256), 0, stream, H, ea, edges, kw1, kb1, kw2, kb2, ws);
        hipLaunchKernelGGL(k_B, dim3(1251), dim3(256), 0, stream, H, w1, b1, g_in, beta_in, ws);
        hipLaunchKernelGGL(k_C, dim3(377),  dim3(256), 0, stream, ea, edges, kw1, kb1, ws);
        hipLaunchKernelGGL(k_D, dim3(1250), dim3(256), 0, stream, g_msg, beta_msg, ws);
        hipLaunchKernelGGL(k_F, dim3(250),  dim3(256), 0, stream, w2, b2, g_upd, beta_upd, ws, out);
        hipLaunchKernelGGL(k_G, dim3((N_*OUTD + 255)/256), dim3(256), 0, stream, g_out, beta_out, ws, out);
    }
}

// Round 8
// 340.450 us; speedup vs baseline: 1.3588x; 1.3588x over previous
//
#include <hip/hip_runtime.h>
#include <math.h>

// ---------------- problem constants ----------------
constexpr int N_    = 10000;
constexpr int E_    = 320000;
constexpr int IND   = 128;
constexpr int HID   = 32;
constexpr int OUTD  = 128;
constexpr int NIV   = 33;      // max intervals = 32 breakpoints + 1
constexpr int NPB   = 20;      // nodes per k_D block (500 blocks x 20 = 10000)
constexpr float EPS = 1e-5f;

// ---------------- workspace layout (element offsets, 4B each) ----
constexpr size_t OFF_SUMH   = 0;       // 128 f
constexpr size_t OFF_SQH    = 128;     // 128 f
constexpr size_t OFF_SUMP   = 256;     // 32 f
constexpr size_t OFF_SQP    = 288;     // 32 f
constexpr size_t OFF_SUMU   = 320;     // 32 f
constexpr size_t OFF_SQU    = 352;     // 32 f
constexpr size_t OFF_SUMO   = 384;     // 128 f
constexpr size_t OFF_SQO    = 512;     // 128 f
constexpr size_t OFF_OCC    = 640;     // 33 i
constexpr size_t OFF_DEGIN  = 704;     // 10000 i
constexpr size_t OFF_DEGOUT = 10704;   // 10000 i
constexpr size_t ZERO_CNT   = 20704;   // elements zeroed by memset
constexpr size_t OFF_STARTS = 20740;   // 10001 i  CSR row starts
constexpr size_t OFF_CUR    = 30744;   // 10000 i  scatter cursors
constexpr size_t OFF_C1     = 40744;   // 33*1056 f
constexpr size_t OFF_C0     = 75592;   // 33*1056 f
constexpr size_t OFF_P      = 110440;  // N*32 f
constexpr size_t OFF_UPD    = 430440;  // N*32 f
constexpr size_t OFF_AEN    = 750440;  // E float2 {a, nin|iv<<14|nl<<20} CSR order

// helper: sorted breakpoints of relu(a*kw1+kb1) — recomputed locally wherever
// needed (NO cross-block data dependence).
__device__ inline int compute_bps(const float* kw1, const float* kb1, float* bp) {
    int m = 0;
    for (int k = 0; k < 32; ++k) {
        float w = kw1[k];
        if (w != 0.f) bp[m++] = -kb1[k] / w;
    }
    for (int a = 1; a < m; ++a) {
        float v = bp[a]; int b = a - 1;
        while (b >= 0 && bp[b] > v) { bp[b+1] = bp[b]; --b; }
        bp[b+1] = v;
    }
    return m;
}

// =======================================================================
// K_A (fused): blocks [0,33) interval tables | [33,161) H stats |
//              [161,474) per-edge interval occupancy + in/out degree
// =======================================================================
__global__ __launch_bounds__(256)
void k_A(const float* __restrict__ H,
         const float* __restrict__ ea, const int* __restrict__ edges,
         const float* __restrict__ kw1, const float* __restrict__ kb1,
         const float* __restrict__ kw2, const float* __restrict__ kb2,
         float* __restrict__ ws) {
    __shared__ float sel1[32], sel0[32];
    __shared__ float shS[256], shQ[256];
    __shared__ int locc[NIV];
    __shared__ float bps[32];
    int* wsi = (int*)ws;
    int t = threadIdx.x;
    int bid = blockIdx.x;

    if (bid < 33) {
        int i = bid;
        if (t == 0) {
            float bp[32];
            int m = compute_bps(kw1, kb1, bp);
            float arep;
            if (m == 0 || i > m) arep = 0.f;
            else if (i == 0)     arep = bp[0]   - (1.f + 0.5f*fabsf(bp[0]));
            else if (i == m)     arep = bp[m-1] + (1.f + 0.5f*fabsf(bp[m-1]));
            else                 arep = (bp[i-1] < bp[i]) ? 0.5f*(bp[i-1] + bp[i]) : bp[i-1];
            for (int k = 0; k < 32; ++k) {
                bool s = (arep * kw1[k] + kb1[k]) > 0.f;
                sel1[k] = s ? kw1[k] : 0.f;
                sel0[k] = s ? kb1[k] : 0.f;
            }
        }
        __syncthreads();
        for (int r = t; r < 1056; r += 256) {
            float a1 = 0.f, a0 = 0.f;
            for (int k = 0; k < 32; ++k) {
                float w = kw2[r*32 + k];
                a1 += w * sel1[k];
                a0 += w * sel0[k];
            }
            ws[OFF_C1 + (size_t)i*1056 + r] = a1;
            ws[OFF_C0 + (size_t)i*1056 + r] = a0 + kb2[r];
        }
    } else if (bid < 161) {
        int b2 = bid - 33;
        int col = t & 127, half = t >> 7;
        float s = 0.f, q = 0.f;
        for (int r = b2*2 + half; r < N_; r += 128*2) {
            float x = H[(size_t)r*IND + col];
            s += x; q += x*x;
        }
        shS[t] = s; shQ[t] = q;
        __syncthreads();
        if (t < 128) {
            atomicAdd(&ws[OFF_SUMH + t], shS[t] + shS[t+128]);
            atomicAdd(&ws[OFF_SQH  + t], shQ[t] + shQ[t+128]);
        }
    } else {
        int b2 = bid - 161;
        if (t < NIV) locc[t] = 0;
        if (t == 0) {
            float bp[32];
            int m = compute_bps(kw1, kb1, bp);
            for (int k = 0; k < 32; ++k) bps[k] = (k < m) ? bp[k] : 3.0e38f;
        }
        __syncthreads();
        for (int e = b2*256 + t; e < E_; e += 313*256) {
            float a = ea[e];
            int cnt = 0;
            #pragma unroll
            for (int k = 0; k < 32; ++k) cnt += (bps[k] < a) ? 1 : 0;
            atomicAdd(&locc[cnt], 1);
            atomicAdd(&wsi[OFF_DEGIN  + edges[E_ + e]], 1);
            atomicAdd(&wsi[OFF_DEGOUT + edges[e]],      1);
        }
        __syncthreads();
        if (t < NIV && locc[t] > 0) atomicAdd(&wsi[OFF_OCC + t], locc[t]);
    }
}

// =======================================================================
// K_B (fused): block 0 = exclusive scan of out-degree -> starts/cur
//              blocks 1..1250 = P = relu(bn_in(H)) @ w1.T + b1
// =======================================================================
__global__ __launch_bounds__(256)
void k_B(const float* __restrict__ H, const float* __restrict__ w1,
         const float* __restrict__ b1, const float* __restrict__ g_in,
         const float* __restrict__ beta_in, float* __restrict__ ws) {
    __shared__ float w1L[32*129];
    __shared__ float xl[8][128];
    __shared__ int part[256];
    int* wsi = (int*)ws;
    int t = threadIdx.x;

    if (blockIdx.x == 0) {
        int base = t * 40;
        int loc[40];
        int s = 0;
        for (int i = 0; i < 40; ++i) {
            int idx = base + i;
            int v = (idx < N_) ? wsi[OFF_DEGOUT + idx] : 0;
            loc[i] = s; s += v;
        }
        part[t] = s;
        __syncthreads();
        for (int off = 1; off < 256; off <<= 1) {
            int add = (t >= off) ? part[t - off] : 0;
            __syncthreads();
            part[t] += add;
            __syncthreads();
        }
        int pre = (t > 0) ? part[t-1] : 0;
        for (int i = 0; i < 40; ++i) {
            int idx = base + i;
            if (idx <= N_) {
                int v = pre + loc[i];
                wsi[OFF_STARTS + idx] = v;
                if (idx < N_) wsi[OFF_CUR + idx] = v;
            }
        }
        return;
    }

    int g = t >> 5, j = t & 31;
    for (int idx = t; idx < 4096; idx += 256)
        w1L[(idx >> 7)*129 + (idx & 127)] = w1[idx];

    int n = (blockIdx.x - 1)*8 + g;
    float4 h4 = ((const float4*)(H + (size_t)n*IND))[j];
    float4 m4 = ((const float4*)(ws + OFF_SUMH))[j];
    float4 q4 = ((const float4*)(ws + OFF_SQH))[j];
    float4 gg = ((const float4*)g_in)[j];
    float4 bb = ((const float4*)beta_in)[j];
    float4 xv;
    {
        float* hp = (float*)&h4; float* mp = (float*)&m4; float* qp = (float*)&q4;
        float* gp = (float*)&gg; float* bp = (float*)&bb; float* xp = (float*)&xv;
        for (int i = 0; i < 4; ++i) {
            float mean = mp[i] * (1.f/N_);
            float var  = qp[i] * (1.f/N_) - mean*mean;
            float istd = 1.f / sqrtf(var + EPS);
            float gc = gp[i]*istd, bc = bp[i] - mean*gc;
            xp[i] = fmaxf(fmaf(gc, hp[i], bc), 0.f);
        }
    }
    ((float4*)&xl[g][0])[j] = xv;
    __syncthreads();
    float p = b1[j];
    const float* wr = &w1L[j*129];
    const float* xr = &xl[g][0];
    #pragma unroll 8
    for (int k = 0; k < 128; ++k) p = fmaf(wr[k], xr[k], p);
    ws[OFF_P + (size_t)n*HID + j] = p;
}

// =======================================================================
// K_C (fused): blocks [0,313) build CSR-ordered records
//              {a, nin | iv<<14 | (nout%NPB)<<20} |
//              [313,377) degree-weighted stats of P (= msg stats over E)
// =======================================================================
__global__ __launch_bounds__(256)
void k_C(const float* __restrict__ ea, const int* __restrict__ edges,
         const float* __restrict__ kw1, const float* __restrict__ kb1,
         float* __restrict__ ws) {
    __shared__ float shS[256], shQ[256];
    __shared__ float bps[32];
    int* wsi = (int*)ws;
    int t = threadIdx.x;
    if (blockIdx.x < 313) {
        if (t == 0) {
            float bp[32];
            int m = compute_bps(kw1, kb1, bp);
            for (int k = 0; k < 32; ++k) bps[k] = (k < m) ? bp[k] : 3.0e38f;
        }
        __syncthreads();
        float2* aen = (float2*)(ws + OFF_AEN);
        int b2 = blockIdx.x;
        for (int e = b2*256 + t; e < E_; e += 313*256) {
            int   nout = edges[e];
            int   nin  = edges[E_ + e];
            float a    = ea[e];
            int iv = 0;
            #pragma unroll
            for (int k = 0; k < 32; ++k) iv += (bps[k] < a) ? 1 : 0;
            int nl = nout % NPB;
            int pos = atomicAdd(&wsi[OFF_CUR + nout], 1);
            float2 rec; rec.x = a;
            rec.y = __int_as_float(nin | (iv << 14) | (nl << 20));
            aen[pos] = rec;
        }
    } else {
        int b2 = blockIdx.x - 313;
        int j = t & 31, cp = t >> 5;
        float s = 0.f, q = 0.f;
        for (int n = b2*8 + cp; n < N_; n += 64*8) {
            float w = (float)wsi[OFF_DEGIN + n];
            float p = ws[OFF_P + (size_t)n*HID + j];
            s += w*p; q += w*p*p;
        }
        shS[t] = s; shQ[t] = q;
        __syncthreads();
        if (t < 32) {
            float S = 0.f, Qq = 0.f;
            for (int c = 0; c < 8; ++c) { S += shS[t + 32*c]; Qq += shQ[t + 32*c]; }
            atomicAdd(&ws[OFF_SUMP + t], S);
            atomicAdd(&ws[OFF_SQP  + t], Qq);
        }
    }
}

// =======================================================================
// K_D: element-parallel segment reduce with LDS-atomic accumulation.
//   Block owns node range [b*NPB, (b+1)*NPB). Threads stream the block's
//   CSR edge span element-parallel (8 edges x 32 cols), accumulating
//   za/zb/suma/cnt per node via ds_add_f32. Then per-node 4x 32x32
//   matvec epilogue from LDS (float4 A rows, stride 36) + fused upd stats.
// =======================================================================
__global__ __launch_bounds__(256)
void k_D(const float* __restrict__ g_msg, const float* __restrict__ beta_msg,
         float* __restrict__ ws) {
    __shared__ __align__(16) float A[4][32*36];   // A1_s0, A0_s0, A1_s1, A0_s1
    __shared__ float Bv[4][32];                   // bias rows
    __shared__ __align__(16) float accZ[NPB][4][32];  // za0, zb0, za1, zb1
    __shared__ float accS[NPB][4];                // suma0, c0, suma1, c1
    __shared__ float accF[NPB][32];               // fallback contributions
    __shared__ float shS[256], shQ[256];
    __shared__ int s_slots[2];
    int* wsi = (int*)ws;
    int t = threadIdx.x, g = t >> 5, j = t & 31;

    if (t == 0) {
        int a0 = -1, a1 = -1;
        for (int i = 0; i < NIV; ++i)
            if (wsi[OFF_OCC + i] > 0) { if (a0 < 0) a0 = i; else if (a1 < 0) a1 = i; }
        s_slots[0] = a0; s_slots[1] = a1;
    }
    // zero LDS accumulators
    for (int idx = t; idx < NPB*4*32; idx += 256) ((float*)accZ)[idx] = 0.f;
    for (int idx = t; idx < NPB*4;    idx += 256) ((float*)accS)[idx] = 0.f;
    for (int idx = t; idx < NPB*32;   idx += 256) ((float*)accF)[idx] = 0.f;
    __syncthreads();
    int s0 = s_slots[0], s1 = s_slots[1];

    for (int idx = t; idx < 1024; idx += 256) {
        int jj = idx >> 5, kk = idx & 31;
        A[0][jj*36+kk] = (s0 >= 0) ? ws[OFF_C1 + (size_t)s0*1056 + 32 + idx] : 0.f;
        A[1][jj*36+kk] = (s0 >= 0) ? ws[OFF_C0 + (size_t)s0*1056 + 32 + idx] : 0.f;
        A[2][jj*36+kk] = (s1 >= 0) ? ws[OFF_C1 + (size_t)s1*1056 + 32 + idx] : 0.f;
        A[3][jj*36+kk] = (s1 >= 0) ? ws[OFF_C0 + (size_t)s1*1056 + 32 + idx] : 0.f;
    }
    if (t < 32) {
        Bv[0][t] = (s0 >= 0) ? ws[OFF_C1 + (size_t)s0*1056 + t] : 0.f;
        Bv[1][t] = (s0 >= 0) ? ws[OFF_C0 + (size_t)s0*1056 + t] : 0.f;
        Bv[2][t] = (s1 >= 0) ? ws[OFF_C1 + (size_t)s1*1056 + t] : 0.f;
        Bv[3][t] = (s1 >= 0) ? ws[OFF_C0 + (size_t)s1*1056 + t] : 0.f;
    }
    // bn_msg constants for column j
    float mP = ws[OFF_SUMP + j] * (1.f/E_);
    float vP = ws[OFF_SQP  + j] * (1.f/E_) - mP*mP;
    float istd = 1.f / sqrtf(vP + EPS);
    float gc = g_msg[j]*istd, bc = beta_msg[j] - mP*gc;
    __syncthreads();

    int n0 = blockIdx.x * NPB;
    int span0 = wsi[OFF_STARTS + n0], span1 = wsi[OFF_STARTS + n0 + NPB];
    const float2* aen = (const float2*)(ws + OFF_AEN);

    // ---- edge phase: element-parallel, 4-deep pipelined ----
    for (int e0 = span0 + g; e0 < span1; e0 += 32) {
        float2 rc[4]; bool v[4]; float pv[4]; int mt[4];
        #pragma unroll
        for (int u = 0; u < 4; ++u) {
            int e = e0 + 8*u;
            v[u] = e < span1;
            rc[u] = v[u] ? aen[e] : make_float2(0.f, __int_as_float(0));
        }
        #pragma unroll
        for (int u = 0; u < 4; ++u) {
            mt[u] = __float_as_int(rc[u].y);
            pv[u] = ws[OFF_P + (size_t)(mt[u] & 0x3FFF)*HID + j];
        }
        #pragma unroll
        for (int u = 0; u < 4; ++u) {
            if (!v[u]) continue;      // uniform within the 32-lane group
            float a  = rc[u].x;
            int   iv = (mt[u] >> 14) & 0x3F;
            int   nl = mt[u] >> 20;
            float qv = fmaxf(fmaf(gc, pv[u], bc), 0.f);
            if (iv == s0) {
                atomicAdd(&accZ[nl][0][j], a*qv);
                atomicAdd(&accZ[nl][1][j], qv);
                if (j == 0) { atomicAdd(&accS[nl][0], a); atomicAdd(&accS[nl][1], 1.f); }
            } else if (iv == s1) {
                atomicAdd(&accZ[nl][2][j], a*qv);
                atomicAdd(&accZ[nl][3][j], qv);
                if (j == 0) { atomicAdd(&accS[nl][2], a); atomicAdd(&accS[nl][3], 1.f); }
            } else {
                // general fallback (not taken with given inputs)
                const float* C1r = ws + OFF_C1 + (size_t)iv*1056;
                const float* C0r = ws + OFF_C0 + (size_t)iv*1056;
                float d1 = 0.f, d0 = 0.f;
                for (int k2 = 0; k2 < 32; ++k2) {
                    float qk = __shfl(qv, (g & 1)*32 + k2, 64);
                    d1 += C1r[32 + j*32 + k2] * qk;
                    d0 += C0r[32 + j*32 + k2] * qk;
                }
                atomicAdd(&accF[nl][j], a*(d1 + C1r[j]) + (d0 + C0r[j]));
            }
        }
    }
    __syncthreads();

    // ---- epilogue: per-node 4x matvec + fused upd stats ----
    float sumS = 0.f, sumQ = 0.f;
    for (int r = 0; r < NPB; r += 8) {
        int nl = r + g;
        if (nl < NPB) {
            float acc = accF[nl][j];
            float sa0 = accS[nl][0], c0 = accS[nl][1];
            float sa1 = accS[nl][2], c1 = accS[nl][3];
            if (s0 >= 0) acc += sa0*Bv[0][j] + c0*Bv[1][j];
            if (s1 >= 0) acc += sa1*Bv[2][j] + c1*Bv[3][j];
            #pragma unroll
            for (int k4 = 0; k4 < 8; ++k4) {
                float4 z0 = *(const float4*)&accZ[nl][0][k4*4];
                float4 z1 = *(const float4*)&accZ[nl][1][k4*4];
                float4 z2 = *(const float4*)&accZ[nl][2][k4*4];
                float4 z3 = *(const float4*)&accZ[nl][3][k4*4];
                float4 a0 = *(const float4*)&A[0][j*36 + k4*4];
                float4 a1 = *(const float4*)&A[1][j*36 + k4*4];
                float4 a2 = *(const float4*)&A[2][j*36 + k4*4];
                float4 a3 = *(const float4*)&A[3][j*36 + k4*4];
                acc += a0.x*z0.x + a0.y*z0.y + a0.z*z0.z + a0.w*z0.w
                     + a1.x*z1.x + a1.y*z1.y + a1.z*z1.z + a1.w*z1.w
                     + a2.x*z2.x + a2.y*z2.y + a2.z*z2.z + a2.w*z2.w
                     + a3.x*z3.x + a3.y*z3.y + a3.z*z3.z + a3.w*z3.w;
            }
            int n = n0 + nl;
            ws[OFF_UPD + (size_t)n*HID + j] = acc;
            sumS += acc; sumQ += acc*acc;
        }
    }
    shS[t] = sumS; shQ[t] = sumQ;
    __syncthreads();
    if (t < 32) {
        float S = 0.f, Qq = 0.f;
        for (int c = 0; c < 8; ++c) { S += shS[t + 32*c]; Qq += shQ[t + 32*c]; }
        atomicAdd(&ws[OFF_SUMU + t], S);
        atomicAdd(&ws[OFF_SQU  + t], Qq);
    }
}

// =======================================================================
// K_F: out_pre = relu(bn(upd)) @ w2.T + b2 ; accumulate out stats
// =======================================================================
__global__ __launch_bounds__(256)
void k_F(const float* __restrict__ w2, const float* __restrict__ b2,
         const float* __restrict__ g_upd, const float* __restrict__ beta_upd,
         float* __restrict__ ws, float* __restrict__ out) {
    __shared__ float U[2][HID];
    __shared__ float shS[256], shQ[256];
    int t = threadIdx.x, nh = t >> 7, o = t & 127;
    float gc = 0.f, bc = 0.f;
    if (o < 32) {
        float m = ws[OFF_SUMU + o]*(1.f/N_);
        float v = ws[OFF_SQU  + o]*(1.f/N_) - m*m;
        float istd = 1.f/sqrtf(v + EPS);
        gc = g_upd[o]*istd; bc = beta_upd[o] - m*gc;
    }
    float w2r[32];
    for (int k = 0; k < 32; ++k) w2r[k] = w2[o*32 + k];
    float bo = b2[o];
    float sO = 0.f, qO = 0.f;
    for (int base = blockIdx.x*2; base < N_; base += gridDim.x*2) {
        int n = base + nh;
        if (o < 32) {
            float u = ws[OFF_UPD + (size_t)n*HID + o];
            U[nh][o] = fmaxf(fmaf(gc, u, bc), 0.f);
        }
        __syncthreads();
        float v = bo;
        for (int k = 0; k < 32; ++k) v = fmaf(w2r[k], U[nh][k], v);
        out[(size_t)n*OUTD + o] = v;
        sO += v; qO += v*v;
        __syncthreads();
    }
    shS[t] = sO; shQ[t] = qO;
    __syncthreads();
    if (t < 128) {
        atomicAdd(&ws[OFF_SUMO + t], shS[t] + shS[t+128]);
        atomicAdd(&ws[OFF_SQO  + t], shQ[t] + shQ[t+128]);
    }
}

// =======================================================================
// K_G: final output batch-norm (in-place)
// =======================================================================
__global__ __launch_bounds__(256)
void k_G(const float* __restrict__ g_out, const float* __restrict__ beta_out,
         const float* __restrict__ ws, float* __restrict__ out) {
    int g = blockIdx.x*blockDim.x + threadIdx.x;
    if (g >= N_*OUTD) return;
    int o = g & 127;
    float m = ws[OFF_SUMO + o]*(1.f/N_);
    float v = ws[OFF_SQO  + o]*(1.f/N_) - m*m;
    float istd = 1.f/sqrtf(v + EPS);
    out[g] = g_out[o]*istd*(out[g] - m) + beta_out[o];
}

// ---------------- launch -----------------------------------------------------
extern "C" void kernel_launch(void* const* d_in, const int* in_sizes, int n_in,
                              void* d_out, int out_size, void* d_ws, size_t ws_size,
                              hipStream_t stream) {
    const float* H        = (const float*)d_in[0];
    const float* ea       = (const float*)d_in[1];
    const int*   edges    = (const int*)  d_in[2];
    const float* w1       = (const float*)d_in[3];
    const float* b1       = (const float*)d_in[4];
    const float* kw1      = (const float*)d_in[5];
    const float* kb1      = (const float*)d_in[6];
    const float* kw2      = (const float*)d_in[7];
    const float* kb2      = (const float*)d_in[8];
    const float* w2       = (const float*)d_in[9];
    const float* b2       = (const float*)d_in[10];
    const float* g_in     = (const float*)d_in[11];
    const float* beta_in  = (const float*)d_in[12];
    const float* g_msg    = (const float*)d_in[13];
    const float* beta_msg = (const float*)d_in[14];
    const float* g_upd    = (const float*)d_in[15];
    const float* beta_upd = (const float*)d_in[16];
    const float* g_out    = (const float*)d_in[17];
    const float* beta_out = (const float*)d_in[18];
    float* ws  = (float*)d_ws;
    float* out = (float*)d_out;

    hipMemsetAsync(d_ws, 0, ZERO_CNT*sizeof(float), stream);
    hipLaunchKernelGGL(k_A, dim3(474),  dim3(256), 0, stream, H, ea, edges, kw1, kb1, kw2, kb2, ws);
    hipLaunchKernelGGL(k_B, dim3(1251), dim3(256), 0, stream, H, w1, b1, g_in, beta_in, ws);
    hipLaunchKernelGGL(k_C, dim3(377),  dim3(256), 0, stream, ea, edges, kw1, kb1, ws);
    hipLaunchKernelGGL(k_D, dim3(N_/NPB), dim3(256), 0, stream, g_msg, beta_msg, ws);
    hipLaunchKernelGGL(k_F, dim3(250),  dim3(256), 0, stream, w2, b2, g_upd, beta_upd, ws, out);
    hipLaunchKernelGGL(k_G, dim3((N_*OUTD + 255)/256), dim3(256), 0, stream, g_out, beta_out, ws, out);
}